// Round 8
// baseline (154.324 us; speedup 1.0000x reference)
//
#include <hip/hip_runtime.h>

#define NT 2000000
#define NE 20000
#define NTILES128 (NT / 128)   // 15625, exact

using bf16x8 = __attribute__((ext_vector_type(8))) __bf16;
using half8  = __attribute__((ext_vector_type(8))) _Float16;
using half2v = __attribute__((ext_vector_type(2))) _Float16;
using f32x4  = __attribute__((ext_vector_type(4))) float;
using f32x2  = __attribute__((ext_vector_type(2))) float;
using fvec4  = __attribute__((ext_vector_type(4))) float;

// hi/lo bf16 split of 8 consecutive f32 (k2 precision)
__device__ __forceinline__ void load_bsplit(const float* __restrict__ p,
                                            bf16x8& hi, bf16x8& lo) {
    fvec4 a = *(const fvec4*)p;
    fvec4 b = *(const fvec4*)(p + 4);
#pragma unroll
    for (int e = 0; e < 4; e++) {
        float v  = a[e];
        __bf16 h = (__bf16)v;
        hi[e]    = h;
        lo[e]    = (__bf16)(v - (float)h);
        float v2  = b[e];
        __bf16 h2 = (__bf16)v2;
        hi[e + 4] = h2;
        lo[e + 4] = (__bf16)(v2 - (float)h2);
    }
}

// 8 consecutive f32 -> f16x8
__device__ __forceinline__ half8 load_h8(const float* __restrict__ p) {
    fvec4 a = *(const fvec4*)p;
    fvec4 b = *(const fvec4*)(p + 4);
    half8 r;
#pragma unroll
    for (int e = 0; e < 4; e++) {
        r[e]     = (_Float16)a[e];
        r[e + 4] = (_Float16)b[e];
    }
    return r;
}

// ---------------- K1: fused phi1 (2 layers) + jagged segment-sum ----------------
// TILE=128 streaming, f16 layer-1 + f16 MFMA, flush = 4 direct fire-and-forget
// atomics per lane (no butterfly: r7 showed the 3-shuffle DS chain + AGPR
// round-trips dominate stalls, not occupancy). (256,3) is the no-spill point;
// tripwire: FETCH_SIZE must stay ~10MB (spills showed 120-226MB in r2/r5).
__global__ __launch_bounds__(256, 3) void k1_phi1(
    const float* __restrict__ values, const int* __restrict__ seg,
    const float* __restrict__ w0, const float* __restrict__ b0,
    const float* __restrict__ w1, const float* __restrict__ b1,
    float* __restrict__ ev) {
    const int tid = threadIdx.x;
    const int w   = tid >> 6;
    const int l   = tid & 63;
    const int l15 = l & 15;
    const int l4  = l >> 4;

    // B fragments for W1 (f16): lane holds col j=16jf+l15, k = 32kf+8*l4+e
    half8 Bh[2][4];
#pragma unroll
    for (int kf = 0; kf < 2; kf++)
#pragma unroll
        for (int jf = 0; jf < 4; jf++)
            Bh[kf][jf] = load_h8(w1 + (jf * 16 + l15) * 64 + kf * 32 + l4 * 8);

    // layer-1 weights as f16 pairs -> v_pk_fma_f16 in the A-build
    half2v w0h[2][4], b0h[2][4];
#pragma unroll
    for (int kf = 0; kf < 2; kf++) {
        const int kb = kf * 32 + l4 * 8;
#pragma unroll
        for (int e2 = 0; e2 < 4; e2++) {
            f32x2 wp = *(const f32x2*)(w0 + kb + 2 * e2);
            f32x2 bp = *(const f32x2*)(b0 + kb + 2 * e2);
            w0h[kf][e2] = half2v{(_Float16)wp[0], (_Float16)wp[1]};
            b0h[kf][e2] = half2v{(_Float16)bp[0], (_Float16)bp[1]};
        }
    }
    // bias as ready-made C fragment
    f32x4 biasC[4];
#pragma unroll
    for (int jf = 0; jf < 4; jf++) {
        const float bj = b1[jf * 16 + l15];
#pragma unroll
        for (int r = 0; r < 4; r++) biasC[jf][r] = bj;
    }

    // flush: 4 fire-and-forget atomics; lanes with same l15 (4-way) merge in TCC
    auto FLUSH = [&](int sid, const float* sj) {
#pragma unroll
        for (int jf = 0; jf < 4; jf++)
            atomicAdd(ev + (size_t)sid * 64 + jf * 16 + l15, sj[jf]);
    };

    const int stride = gridDim.x * 4;          // 768 blocks -> 3072 waves
    int tile = blockIdx.x * 4 + w;             // < 3072 <= NTILES128: valid

    int sA = seg[tile * 128 + l];
    int sB = seg[tile * 128 + 64 + l];
    half2v vph[4];
#pragma unroll
    for (int b = 0; b < 8; b++)
        vph[b >> 1][b & 1] = (_Float16)values[tile * 128 + b * 16 + l15];

    while (tile < NTILES128) {
        // ---- prefetch next tile (uniform guard) ----
        const int ntile = tile + stride;
        int sAn = 0, sBn = 0;
        half2v vpn[4];
#pragma unroll
        for (int i = 0; i < 4; i++) vpn[i] = half2v{(_Float16)0.f, (_Float16)0.f};
        if (ntile < NTILES128) {
            const int nb = ntile * 128;
            sAn = seg[nb + l];
            sBn = seg[nb + 64 + l];
#pragma unroll
            for (int b = 0; b < 8; b++)
                vpn[b >> 1][b & 1] = (_Float16)values[nb + b * 16 + l15];
        }

        // boundary masks for the two 64-chunks (chunk-B bit0 = A->B boundary)
        const int prevA = __shfl_up(sA, 1);
        const unsigned long long mA = __ballot((l > 0) && (sA != prevA));
        const int lastA = __builtin_amdgcn_readlane(sA, 63);
        int prevB = __shfl_up(sB, 1);
        prevB = (l == 0) ? lastA : prevB;
        const unsigned long long mB = __ballot(sB != prevB);

        int   cur = __builtin_amdgcn_readlane(sA, 0);
        float sj[4] = {0.f, 0.f, 0.f, 0.f};

#pragma unroll
        for (int b = 0; b < 8; b++) {          // 16-row block
            const unsigned mask16 =
                (unsigned)(((b < 4 ? mA : mB) >> (16 * (b & 3))) & 0xFFFFull);
            const _Float16 vh = vph[b >> 1][b & 1];
            const half2v vv = {vh, vh};

            // A frags (both kf): h1 = relu(v*w0+b0) in packed f16
            half8 A0, A1;
#pragma unroll
            for (int e2 = 0; e2 < 4; e2++) {
                half2v h0 = vv * w0h[0][e2] + b0h[0][e2];   // v_pk_fma_f16
                half2v h1 = vv * w0h[1][e2] + b0h[1][e2];
                const _Float16 z = (_Float16)0.f;
                A0[2 * e2]     = h0[0] > z ? h0[0] : z;
                A0[2 * e2 + 1] = h0[1] > z ? h0[1] : z;
                A1[2 * e2]     = h1[0] > z ? h1[0] : z;
                A1[2 * e2 + 1] = h1[1] > z ? h1[1] : z;
            }

            // 2-MFMA chain per jf, relu'd into frag (streaming)
            f32x4 frag[4];
#pragma unroll
            for (int jf = 0; jf < 4; jf++) {
                f32x4 t = __builtin_amdgcn_mfma_f32_16x16x32_f16(
                    A0, Bh[0][jf], biasC[jf], 0, 0, 0);
                t = __builtin_amdgcn_mfma_f32_16x16x32_f16(
                    A1, Bh[1][jf], t, 0, 0, 0);
#pragma unroll
                for (int r = 0; r < 4; r++) frag[jf][r] = fmaxf(t[r], 0.f);
            }

            if (mask16 == 0u) {
#pragma unroll
                for (int jf = 0; jf < 4; jf++)
                    sj[jf] += (frag[jf][0] + frag[jf][1]) +
                              (frag[jf][2] + frag[jf][3]);
            } else {
                unsigned m = mask16;
                int start = 0;
                while (true) {
                    const int e = m ? (int)__builtin_ctz(m) : 16;
#pragma unroll
                    for (int jf = 0; jf < 4; jf++) {
                        float s = 0.f;
#pragma unroll
                        for (int r = 0; r < 4; r++) {
                            const int rel = l4 * 4 + r;
                            s += (rel >= start && rel < e) ? frag[jf][r] : 0.f;
                        }
                        sj[jf] += s;
                    }
                    if (!m) break;
                    FLUSH(cur, sj);
                    sj[0] = sj[1] = sj[2] = sj[3] = 0.f;
                    cur = __builtin_amdgcn_readlane(b < 4 ? sA : sB,
                                                    16 * (b & 3) + e);
                    start = e;
                    m &= (m - 1);
                }
            }
        }
        FLUSH(cur, sj);                        // tile-end flush

        // rotate prefetched state
        tile = ntile;
        sA = sAn;
        sB = sBn;
#pragma unroll
        for (int i = 0; i < 4; i++) vph[i] = vpn[i];
    }
}

// ------- K2: rho1 + o1 + phi2 (5 fused layers) + event-sum + fused rho2 tail -------
__global__ __launch_bounds__(64) void k2_events(
    const float* __restrict__ ev,
    const float* __restrict__ W0, const float* __restrict__ B0,
    const float* __restrict__ W1, const float* __restrict__ B1,
    const float* __restrict__ W2, const float* __restrict__ B2,
    const float* __restrict__ W3, const float* __restrict__ B3,
    const float* __restrict__ W4, const float* __restrict__ B4,
    float* __restrict__ s2, int* __restrict__ counter,
    const float* __restrict__ R0, const float* __restrict__ Rb0,
    const float* __restrict__ R1, const float* __restrict__ Rb1,
    const float* __restrict__ OW, const float* __restrict__ OB,
    float* __restrict__ out) {
    __shared__ __align__(16) __bf16 xt[64 * 72];   // [e][k], stride 72
    const int l   = threadIdx.x;
    const int l15 = l & 15;
    const int l4  = l >> 4;
    const int ebase = blockIdx.x * 64;

    const float* Ws[5] = {W0, W1, W2, W3, W4};
    const float* Bs[5] = {B0, B1, B2, B3, B4};

    bf16x8 A[4][2];
#pragma unroll
    for (int pf = 0; pf < 4; pf++) {
        const int e = ebase + pf * 16 + l15;
#pragma unroll
        for (int kf = 0; kf < 2; kf++) {
            bf16x8 a;
            if (e < NE) {
                const float* p = ev + (size_t)e * 64 + kf * 32 + l4 * 8;
                fvec4 x = *(const fvec4*)p;
                fvec4 y = *(const fvec4*)(p + 4);
#pragma unroll
                for (int e2 = 0; e2 < 4; e2++) {
                    a[e2]     = (__bf16)x[e2];
                    a[e2 + 4] = (__bf16)y[e2];
                }
            } else {
#pragma unroll
                for (int e2 = 0; e2 < 8; e2++) a[e2] = (__bf16)0.f;
            }
            A[pf][kf] = a;
        }
    }

#pragma unroll
    for (int L = 0; L < 5; L++) {
        bf16x8 Bh[2][4], Bl[2][4];
#pragma unroll
        for (int kf = 0; kf < 2; kf++)
#pragma unroll
            for (int jf = 0; jf < 4; jf++)
                load_bsplit(Ws[L] + (jf * 16 + l15) * 64 + kf * 32 + l4 * 8,
                            Bh[kf][jf], Bl[kf][jf]);

        f32x4 acc[4][4];
#pragma unroll
        for (int jf = 0; jf < 4; jf++) {
            const float bj = Bs[L][jf * 16 + l15];
#pragma unroll
            for (int pf = 0; pf < 4; pf++)
#pragma unroll
                for (int r = 0; r < 4; r++) acc[pf][jf][r] = bj;
        }
#pragma unroll
        for (int kf = 0; kf < 2; kf++)
#pragma unroll
            for (int pf = 0; pf < 4; pf++)
#pragma unroll
                for (int jf = 0; jf < 4; jf++)
                    acc[pf][jf] = __builtin_amdgcn_mfma_f32_16x16x32_bf16(
                        A[pf][kf], Bh[kf][jf], acc[pf][jf], 0, 0, 0);
#pragma unroll
        for (int kf = 0; kf < 2; kf++)
#pragma unroll
            for (int pf = 0; pf < 4; pf++)
#pragma unroll
                for (int jf = 0; jf < 4; jf++)
                    acc[pf][jf] = __builtin_amdgcn_mfma_f32_16x16x32_bf16(
                        A[pf][kf], Bl[kf][jf], acc[pf][jf], 0, 0, 0);

        if (L < 4) {
#pragma unroll
            for (int pf = 0; pf < 4; pf++)
#pragma unroll
                for (int jf = 0; jf < 4; jf++) {
                    const int j = jf * 16 + l15;
#pragma unroll
                    for (int r = 0; r < 4; r++)
                        xt[(pf * 16 + l4 * 4 + r) * 72 + j] =
                            (__bf16)fmaxf(acc[pf][jf][r], 0.f);
                }
#pragma unroll
            for (int pf = 0; pf < 4; pf++)
#pragma unroll
                for (int kf = 0; kf < 2; kf++)
                    A[pf][kf] = *(const bf16x8*)(xt + (pf * 16 + l15) * 72 +
                                                 kf * 32 + l4 * 8);
        } else {
            float sj[4];
#pragma unroll
            for (int jf = 0; jf < 4; jf++) {
                float s = 0.f;
#pragma unroll
                for (int pf = 0; pf < 4; pf++)
#pragma unroll
                    for (int r = 0; r < 4; r++) {
                        const int e = ebase + pf * 16 + l4 * 4 + r;
                        float v = fmaxf(acc[pf][jf][r], 0.f);
                        s += (e < NE) ? v : 0.f;
                    }
                s += __shfl_xor(s, 16);
                s += __shfl_xor(s, 32);
                sj[jf] = s;
            }
            float v = (l4 == 0) ? sj[0] : (l4 == 1) ? sj[1]
                    : (l4 == 2) ? sj[2] : sj[3];
            atomicAdd(s2 + l, v);
        }
    }

    // ---- fused rho2 + output + log_softmax: last block to finish does it ----
    __shared__ int is_last;
    __threadfence();
    if (l == 0) {
        const int c = atomicAdd(counter, 1);
        is_last = (c == (int)gridDim.x - 1);
    }
    __syncthreads();
    if (!is_last) return;

    __shared__ __align__(16) float xb[64];
    __shared__ __align__(16) float yb[64];
    __shared__ float ob[10];

    // coherent read of s2 (other blocks' atomics visible via fence+counter)
    xb[l] = atomicAdd(s2 + l, 0.f);
    __syncthreads();

    float a0 = Rb0[l];
#pragma unroll
    for (int k = 0; k < 16; k++) {
        fvec4 wv = *(const fvec4*)(R0 + l * 64 + k * 4);
        fvec4 xv = *(const fvec4*)(xb + k * 4);
        a0 += wv[0] * xv[0] + wv[1] * xv[1] + wv[2] * xv[2] + wv[3] * xv[3];
    }
    yb[l] = fmaxf(a0, 0.f);
    __syncthreads();

    float b_ = Rb1[l];
#pragma unroll
    for (int k = 0; k < 16; k++) {
        fvec4 wv = *(const fvec4*)(R1 + l * 64 + k * 4);
        fvec4 xv = *(const fvec4*)(yb + k * 4);
        b_ += wv[0] * xv[0] + wv[1] * xv[1] + wv[2] * xv[2] + wv[3] * xv[3];
    }
    __syncthreads();
    xb[l] = fmaxf(b_, 0.f);
    __syncthreads();

    if (l < 10) {
        float o = OB[l];
#pragma unroll
        for (int k = 0; k < 16; k++) {
            fvec4 wv = *(const fvec4*)(OW + l * 64 + k * 4);
            fvec4 xv = *(const fvec4*)(xb + k * 4);
            o += wv[0] * xv[0] + wv[1] * xv[1] + wv[2] * xv[2] + wv[3] * xv[3];
        }
        ob[l] = o;
    }
    __syncthreads();
    if (l == 0) {
        float m = ob[0];
#pragma unroll
        for (int i = 1; i < 10; i++) m = fmaxf(m, ob[i]);
        float sum = 0.f;
#pragma unroll
        for (int i = 0; i < 10; i++) sum = sum + expf(ob[i] - m);
        float ls = logf(sum);
#pragma unroll
        for (int i = 0; i < 10; i++) out[i] = ob[i] - m - ls;
    }
}

extern "C" void kernel_launch(void* const* d_in, const int* in_sizes, int n_in,
                              void* d_out, int out_size, void* d_ws, size_t ws_size,
                              hipStream_t stream) {
    const float* values = (const float*)d_in[0];
    const int*   seg    = (const int*)d_in[1];
    const float* p1w0 = (const float*)d_in[2],  *p1b0 = (const float*)d_in[3];
    const float* p1w1 = (const float*)d_in[4],  *p1b1 = (const float*)d_in[5];
    const float* r1w0 = (const float*)d_in[6],  *r1b0 = (const float*)d_in[7];
    const float* r1w1 = (const float*)d_in[8],  *r1b1 = (const float*)d_in[9];
    const float* o1w  = (const float*)d_in[10], *o1b  = (const float*)d_in[11];
    const float* p2w0 = (const float*)d_in[12], *p2b0 = (const float*)d_in[13];
    const float* p2w1 = (const float*)d_in[14], *p2b1 = (const float*)d_in[15];
    const float* r2w0 = (const float*)d_in[16], *r2b0 = (const float*)d_in[17];
    const float* r2w1 = (const float*)d_in[18], *r2b1 = (const float*)d_in[19];
    const float* o2w  = (const float*)d_in[20], *o2b  = (const float*)d_in[21];

    float* ev = (float*)d_ws;                       // [NE][64] accumulators
    float* s2 = ev + (size_t)NE * 64;               // [64]
    int* counter = (int*)(s2 + 64);                 // [1]

    hipMemsetAsync(d_ws, 0, (size_t)(NE * 64 + 64) * sizeof(float) + sizeof(int),
                   stream);

    hipLaunchKernelGGL(k1_phi1, dim3(768), dim3(256), 0, stream,
                       values, seg, p1w0, p1b0, p1w1, p1b1, ev);
    hipLaunchKernelGGL(k2_events, dim3((NE + 63) / 64), dim3(64), 0, stream,
                       ev, r1w0, r1b0, r1w1, r1b1, o1w, o1b,
                       p2w0, p2b0, p2w1, p2b1, s2, counter,
                       r2w0, r2b0, r2w1, r2b1, o2w, o2b, (float*)d_out);
}

// Round 9
// 72.999 us; speedup vs baseline: 2.1140x; 2.1140x over previous
//
#include <hip/hip_runtime.h>

#define NT 2000000
#define NE 20000
#define NTILES (NT / 64)      // 31250, exact
#define K1_BLOCKS 1024
#define K1_WAVES (K1_BLOCKS * 4)   // 4096
#define TILES_BASE (NTILES / K1_WAVES)          // 7
#define TILES_REM (NTILES - TILES_BASE * K1_WAVES)  // 2578
#define STAGE_CAP 24          // avg flushes/wave ~7.5; overflow -> atomic

using bf16x8 = __attribute__((ext_vector_type(8))) __bf16;
using half8  = __attribute__((ext_vector_type(8))) _Float16;
using half2v = __attribute__((ext_vector_type(2))) _Float16;
using f32x4  = __attribute__((ext_vector_type(4))) float;
using f32x2  = __attribute__((ext_vector_type(2))) float;
using fvec4  = __attribute__((ext_vector_type(4))) float;

// hi/lo bf16 split of 8 consecutive f32 (k2 precision)
__device__ __forceinline__ void load_bsplit(const float* __restrict__ p,
                                            bf16x8& hi, bf16x8& lo) {
    fvec4 a = *(const fvec4*)p;
    fvec4 b = *(const fvec4*)(p + 4);
#pragma unroll
    for (int e = 0; e < 4; e++) {
        float v  = a[e];
        __bf16 h = (__bf16)v;
        hi[e]    = h;
        lo[e]    = (__bf16)(v - (float)h);
        float v2  = b[e];
        __bf16 h2 = (__bf16)v2;
        hi[e + 4] = h2;
        lo[e + 4] = (__bf16)(v2 - (float)h2);
    }
}

// 8 consecutive f32 -> f16x8
__device__ __forceinline__ half8 load_h8(const float* __restrict__ p) {
    fvec4 a = *(const fvec4*)p;
    fvec4 b = *(const fvec4*)(p + 4);
    half8 r;
#pragma unroll
    for (int e = 0; e < 4; e++) {
        r[e]     = (_Float16)a[e];
        r[e + 4] = (_Float16)b[e];
    }
    return r;
}

// ---------------- K1: fused phi1 (2 layers) + jagged segment-sum ----------------
// Carry + contiguous ranges + STAGED flushes (no atomics in the hot loop).
// Theory (r4-r7 post-mortem): in-loop device-scope atomics (~700cy at the
// coherence point) + the variable-count run loop forcing s_waitcnt vmcnt(0)
// at every tile top were the serial wall. Staged: flush -> plain store into
// stage[wid][c][64]; combiner kernel does the dependency-free atomics.
// Fallback (use_stage==0, ws too small): carry + direct atomic flush.
// Tripwire: FETCH_SIZE must stay ~8-11MB (spills showed 120-226MB r2/r5).
__global__ __launch_bounds__(256, 4) void k1_phi1(
    const float* __restrict__ values, const int* __restrict__ seg,
    const float* __restrict__ w0, const float* __restrict__ b0,
    const float* __restrict__ w1, const float* __restrict__ b1,
    float* __restrict__ ev,
    float* __restrict__ stage, int* __restrict__ sid_arr,
    int* __restrict__ cnt_arr, int use_stage) {
    const int tid = threadIdx.x;
    const int w   = tid >> 6;
    const int l   = tid & 63;
    const int l15 = l & 15;
    const int l4  = l >> 4;

    // B fragments for W1 (f16): lane holds col j=16jf+l15, k = 32kf+8*l4+e
    half8 Bh[2][4];
#pragma unroll
    for (int kf = 0; kf < 2; kf++)
#pragma unroll
        for (int jf = 0; jf < 4; jf++)
            Bh[kf][jf] = load_h8(w1 + (jf * 16 + l15) * 64 + kf * 32 + l4 * 8);

    // layer-1 weights as f16 pairs -> v_pk_fma_f16 in the A-build
    half2v w0h[2][4], b0h[2][4];
#pragma unroll
    for (int kf = 0; kf < 2; kf++) {
        const int kb = kf * 32 + l4 * 8;
#pragma unroll
        for (int e2 = 0; e2 < 4; e2++) {
            f32x2 wp = *(const f32x2*)(w0 + kb + 2 * e2);
            f32x2 bp = *(const f32x2*)(b0 + kb + 2 * e2);
            w0h[kf][e2] = half2v{(_Float16)wp[0], (_Float16)wp[1]};
            b0h[kf][e2] = half2v{(_Float16)bp[0], (_Float16)bp[1]};
        }
    }
    // bias as ready-made C fragment
    f32x4 biasC[4];
#pragma unroll
    for (int jf = 0; jf < 4; jf++) {
        const float bj = b1[jf * 16 + l15];
#pragma unroll
        for (int r = 0; r < 4; r++) biasC[jf][r] = bj;
    }

    // 2-step butterfly: lane l ends holding full column sum of feature j==l
    const bool bit0 = (l & 16) != 0;
    const bool bit1 = (l & 32) != 0;
    auto reduce4 = [&](const float sj[4]) -> float {
        float send01 = bit0 ? sj[0] : sj[1];
        float keep01 = bit0 ? sj[1] : sj[0];
        float c01 = keep01 + __shfl_xor(send01, 16);
        float send23 = bit0 ? sj[2] : sj[3];
        float keep23 = bit0 ? sj[3] : sj[2];
        float c23 = keep23 + __shfl_xor(send23, 16);
        float send = bit1 ? c01 : c23;
        float keep = bit1 ? c23 : c01;
        return keep + __shfl_xor(send, 32);
    };

    const int wid   = blockIdx.x * 4 + w;
    const int start = wid * TILES_BASE + (wid < TILES_REM ? wid : TILES_REM);
    const int end   = start + TILES_BASE + (wid < TILES_REM ? 1 : 0);

    int nf = 0;
    auto FLUSH = [&](int sid, float* sj) {
        const float v = reduce4(sj);
        if (use_stage && nf < STAGE_CAP) {
            const int slot = wid * STAGE_CAP + nf;
            stage[(size_t)slot * 64 + l] = v;
            if (l == 0) sid_arr[slot] = sid;
            nf++;
        } else {
            atomicAdd(ev + (size_t)sid * 64 + l, v);
        }
    };

    // preload first tile
    int t = start;
    int s_cur = seg[t * 64 + l];
    half2v vph[2];
#pragma unroll
    for (int b = 0; b < 4; b++)
        vph[b >> 1][b & 1] = (_Float16)values[t * 64 + b * 16 + l15];

    int   cur = __builtin_amdgcn_readlane(s_cur, 0);
    float sj[4] = {0.f, 0.f, 0.f, 0.f};

    while (t < end) {
        // ---- prefetch next tile (uniform guard) ----
        const int nt = t + 1;
        int s_nxt = 0;
        half2v vpn[2];
#pragma unroll
        for (int i = 0; i < 2; i++) vpn[i] = half2v{(_Float16)0.f, (_Float16)0.f};
        if (nt < end) {
            s_nxt = seg[nt * 64 + l];
#pragma unroll
            for (int b = 0; b < 4; b++)
                vpn[b >> 1][b & 1] = (_Float16)values[nt * 64 + b * 16 + l15];
        }

        // boundary mask; lane0 compares against carried event id
        const int prev = __shfl_up(s_cur, 1);
        const bool diff = (l == 0) ? (s_cur != cur) : (s_cur != prev);
        const unsigned long long mask = __ballot(diff);

#pragma unroll
        for (int b = 0; b < 4; b++) {          // 16-row block
            const unsigned mask16 = (unsigned)((mask >> (16 * b)) & 0xFFFFull);
            const _Float16 vh = vph[b >> 1][b & 1];
            const half2v vv = {vh, vh};

            // A frags (both kf): h1 = relu(v*w0+b0) in packed f16
            half8 A0, A1;
#pragma unroll
            for (int e2 = 0; e2 < 4; e2++) {
                half2v h0 = vv * w0h[0][e2] + b0h[0][e2];   // v_pk_fma_f16
                half2v h1 = vv * w0h[1][e2] + b0h[1][e2];
                const _Float16 z = (_Float16)0.f;
                A0[2 * e2]     = h0[0] > z ? h0[0] : z;
                A0[2 * e2 + 1] = h0[1] > z ? h0[1] : z;
                A1[2 * e2]     = h1[0] > z ? h1[0] : z;
                A1[2 * e2 + 1] = h1[1] > z ? h1[1] : z;
            }

            // 2-MFMA chain per jf, relu'd into frag (streaming)
            f32x4 frag[4];
#pragma unroll
            for (int jf = 0; jf < 4; jf++) {
                f32x4 tt = __builtin_amdgcn_mfma_f32_16x16x32_f16(
                    A0, Bh[0][jf], biasC[jf], 0, 0, 0);
                tt = __builtin_amdgcn_mfma_f32_16x16x32_f16(
                    A1, Bh[1][jf], tt, 0, 0, 0);
#pragma unroll
                for (int r = 0; r < 4; r++) frag[jf][r] = fmaxf(tt[r], 0.f);
            }

            if (mask16 == 0u) {
#pragma unroll
                for (int jf = 0; jf < 4; jf++)
                    sj[jf] += (frag[jf][0] + frag[jf][1]) +
                              (frag[jf][2] + frag[jf][3]);
            } else {
                unsigned m = mask16;
                int st = 0;
                while (true) {
                    const int e = m ? (int)__builtin_ctz(m) : 16;
#pragma unroll
                    for (int jf = 0; jf < 4; jf++) {
                        float s = 0.f;
#pragma unroll
                        for (int r = 0; r < 4; r++) {
                            const int rel = l4 * 4 + r;
                            s += (rel >= st && rel < e) ? frag[jf][r] : 0.f;
                        }
                        sj[jf] += s;
                    }
                    if (!m) break;
                    FLUSH(cur, sj);
                    sj[0] = sj[1] = sj[2] = sj[3] = 0.f;
                    cur = __builtin_amdgcn_readlane(s_cur, 16 * b + e);
                    st  = e;
                    m &= (m - 1);
                }
            }
        }

        // rotate prefetched state (carry cur/sj across tiles)
        t = nt;
        s_cur = s_nxt;
        vph[0] = vpn[0];
        vph[1] = vpn[1];
    }
    FLUSH(cur, sj);                            // range-end flush
    if (use_stage && l == 0) cnt_arr[wid] = nf;
}

// ---------------- K1b: combine staged partials into ev (dependency-free atomics) --
__global__ __launch_bounds__(256) void k1_combine(
    const float* __restrict__ stage, const int* __restrict__ sid_arr,
    const int* __restrict__ cnt_arr, float* __restrict__ ev) {
    const int w = threadIdx.x >> 6, l = threadIdx.x & 63;
    const int wid = blockIdx.x * 4 + w;
    const int n = cnt_arr[wid];
    for (int c = 0; c < n; ++c) {
        const int slot = wid * STAGE_CAP + c;
        const int sid  = sid_arr[slot];
        atomicAdd(ev + (size_t)sid * 64 + l, stage[(size_t)slot * 64 + l]);
    }
}

// ---------------- K2: rho1 + o1 + phi2 (5 fused 64x64 layers) + event-sum --------
__global__ __launch_bounds__(64) void k2_events(
    const float* __restrict__ ev,
    const float* __restrict__ W0, const float* __restrict__ B0,
    const float* __restrict__ W1, const float* __restrict__ B1,
    const float* __restrict__ W2, const float* __restrict__ B2,
    const float* __restrict__ W3, const float* __restrict__ B3,
    const float* __restrict__ W4, const float* __restrict__ B4,
    float* __restrict__ s2) {
    __shared__ __align__(16) __bf16 xt[64 * 72];   // [e][k], stride 72
    const int l   = threadIdx.x;
    const int l15 = l & 15;
    const int l4  = l >> 4;
    const int ebase = blockIdx.x * 64;

    const float* Ws[5] = {W0, W1, W2, W3, W4};
    const float* Bs[5] = {B0, B1, B2, B3, B4};

    bf16x8 A[4][2];
#pragma unroll
    for (int pf = 0; pf < 4; pf++) {
        const int e = ebase + pf * 16 + l15;
#pragma unroll
        for (int kf = 0; kf < 2; kf++) {
            bf16x8 a;
            if (e < NE) {
                const float* p = ev + (size_t)e * 64 + kf * 32 + l4 * 8;
                fvec4 x = *(const fvec4*)p;
                fvec4 y = *(const fvec4*)(p + 4);
#pragma unroll
                for (int e2 = 0; e2 < 4; e2++) {
                    a[e2]     = (__bf16)x[e2];
                    a[e2 + 4] = (__bf16)y[e2];
                }
            } else {
#pragma unroll
                for (int e2 = 0; e2 < 8; e2++) a[e2] = (__bf16)0.f;
            }
            A[pf][kf] = a;
        }
    }

#pragma unroll
    for (int L = 0; L < 5; L++) {
        bf16x8 Bh[2][4], Bl[2][4];
#pragma unroll
        for (int kf = 0; kf < 2; kf++)
#pragma unroll
            for (int jf = 0; jf < 4; jf++)
                load_bsplit(Ws[L] + (jf * 16 + l15) * 64 + kf * 32 + l4 * 8,
                            Bh[kf][jf], Bl[kf][jf]);

        f32x4 acc[4][4];
#pragma unroll
        for (int jf = 0; jf < 4; jf++) {
            const float bj = Bs[L][jf * 16 + l15];
#pragma unroll
            for (int pf = 0; pf < 4; pf++)
#pragma unroll
                for (int r = 0; r < 4; r++) acc[pf][jf][r] = bj;
        }
#pragma unroll
        for (int kf = 0; kf < 2; kf++)
#pragma unroll
            for (int pf = 0; pf < 4; pf++)
#pragma unroll
                for (int jf = 0; jf < 4; jf++)
                    acc[pf][jf] = __builtin_amdgcn_mfma_f32_16x16x32_bf16(
                        A[pf][kf], Bh[kf][jf], acc[pf][jf], 0, 0, 0);
#pragma unroll
        for (int kf = 0; kf < 2; kf++)
#pragma unroll
            for (int pf = 0; pf < 4; pf++)
#pragma unroll
                for (int jf = 0; jf < 4; jf++)
                    acc[pf][jf] = __builtin_amdgcn_mfma_f32_16x16x32_bf16(
                        A[pf][kf], Bl[kf][jf], acc[pf][jf], 0, 0, 0);

        if (L < 4) {
#pragma unroll
            for (int pf = 0; pf < 4; pf++)
#pragma unroll
                for (int jf = 0; jf < 4; jf++) {
                    const int j = jf * 16 + l15;
#pragma unroll
                    for (int r = 0; r < 4; r++)
                        xt[(pf * 16 + l4 * 4 + r) * 72 + j] =
                            (__bf16)fmaxf(acc[pf][jf][r], 0.f);
                }
#pragma unroll
            for (int pf = 0; pf < 4; pf++)
#pragma unroll
                for (int kf = 0; kf < 2; kf++)
                    A[pf][kf] = *(const bf16x8*)(xt + (pf * 16 + l15) * 72 +
                                                 kf * 32 + l4 * 8);
        } else {
            float sj[4];
#pragma unroll
            for (int jf = 0; jf < 4; jf++) {
                float s = 0.f;
#pragma unroll
                for (int pf = 0; pf < 4; pf++)
#pragma unroll
                    for (int r = 0; r < 4; r++) {
                        const int e = ebase + pf * 16 + l4 * 4 + r;
                        float v = fmaxf(acc[pf][jf][r], 0.f);
                        s += (e < NE) ? v : 0.f;
                    }
                s += __shfl_xor(s, 16);
                s += __shfl_xor(s, 32);
                sj[jf] = s;
            }
            float v = (l4 == 0) ? sj[0] : (l4 == 1) ? sj[1]
                    : (l4 == 2) ? sj[2] : sj[3];
            atomicAdd(s2 + l, v);
        }
    }
}

// ---------------- K3: rho2 + output + log_softmax (tiny) ----------------
__global__ __launch_bounds__(64) void k3_final(
    const float* __restrict__ s2,
    const float* __restrict__ W0, const float* __restrict__ B0,
    const float* __restrict__ W1, const float* __restrict__ B1,
    const float* __restrict__ W2, const float* __restrict__ B2,
    float* __restrict__ out) {
    __shared__ __align__(16) float xb[64];
    __shared__ __align__(16) float yb[64];
    __shared__ float ob[10];
    const int l = threadIdx.x;

    xb[l] = s2[l];
    __syncthreads();

    float a = B0[l];
#pragma unroll
    for (int k = 0; k < 16; k++) {
        fvec4 wv = *(const fvec4*)(W0 + l * 64 + k * 4);
        fvec4 xv = *(const fvec4*)(xb + k * 4);
        a += wv[0] * xv[0] + wv[1] * xv[1] + wv[2] * xv[2] + wv[3] * xv[3];
    }
    yb[l] = fmaxf(a, 0.f);
    __syncthreads();

    float b_ = B1[l];
#pragma unroll
    for (int k = 0; k < 16; k++) {
        fvec4 wv = *(const fvec4*)(W1 + l * 64 + k * 4);
        fvec4 xv = *(const fvec4*)(yb + k * 4);
        b_ += wv[0] * xv[0] + wv[1] * xv[1] + wv[2] * xv[2] + wv[3] * xv[3];
    }
    __syncthreads();
    xb[l] = fmaxf(b_, 0.f);
    __syncthreads();

    if (l < 10) {
        float o = B2[l];
#pragma unroll
        for (int k = 0; k < 16; k++) {
            fvec4 wv = *(const fvec4*)(W2 + l * 64 + k * 4);
            fvec4 xv = *(const fvec4*)(xb + k * 4);
            o += wv[0] * xv[0] + wv[1] * xv[1] + wv[2] * xv[2] + wv[3] * xv[3];
        }
        ob[l] = o;
    }
    __syncthreads();
    if (l == 0) {
        float m = ob[0];
#pragma unroll
        for (int i = 1; i < 10; i++) m = fmaxf(m, ob[i]);
        float sum = 0.f;
#pragma unroll
        for (int i = 0; i < 10; i++) sum = sum + expf(ob[i] - m);
        float ls = logf(sum);
#pragma unroll
        for (int i = 0; i < 10; i++) out[i] = ob[i] - m - ls;
    }
}

extern "C" void kernel_launch(void* const* d_in, const int* in_sizes, int n_in,
                              void* d_out, int out_size, void* d_ws, size_t ws_size,
                              hipStream_t stream) {
    const float* values = (const float*)d_in[0];
    const int*   seg    = (const int*)d_in[1];
    const float* p1w0 = (const float*)d_in[2],  *p1b0 = (const float*)d_in[3];
    const float* p1w1 = (const float*)d_in[4],  *p1b1 = (const float*)d_in[5];
    const float* r1w0 = (const float*)d_in[6],  *r1b0 = (const float*)d_in[7];
    const float* r1w1 = (const float*)d_in[8],  *r1b1 = (const float*)d_in[9];
    const float* o1w  = (const float*)d_in[10], *o1b  = (const float*)d_in[11];
    const float* p2w0 = (const float*)d_in[12], *p2b0 = (const float*)d_in[13];
    const float* p2w1 = (const float*)d_in[14], *p2b1 = (const float*)d_in[15];
    const float* r2w0 = (const float*)d_in[16], *r2b0 = (const float*)d_in[17];
    const float* r2w1 = (const float*)d_in[18], *r2b1 = (const float*)d_in[19];
    const float* o2w  = (const float*)d_in[20], *o2b  = (const float*)d_in[21];

    float* ev = (float*)d_ws;                       // [NE][64] accumulators
    float* s2 = ev + (size_t)NE * 64;               // [64]
    int*   cnt_arr = (int*)(s2 + 64);               // [K1_WAVES]
    int*   sid_arr = cnt_arr + K1_WAVES;            // [K1_WAVES*STAGE_CAP]
    float* stage   = (float*)(sid_arr + (size_t)K1_WAVES * STAGE_CAP);

    const size_t need = ((size_t)NE * 64 + 64) * 4 +
                        (size_t)K1_WAVES * 4 +
                        (size_t)K1_WAVES * STAGE_CAP * 4 +
                        (size_t)K1_WAVES * STAGE_CAP * 64 * 4;   // ~30.7 MB
    const int use_stage = (ws_size >= need) ? 1 : 0;

    hipMemsetAsync(d_ws, 0, (size_t)(NE * 64 + 64) * sizeof(float), stream);

    hipLaunchKernelGGL(k1_phi1, dim3(K1_BLOCKS), dim3(256), 0, stream,
                       values, seg, p1w0, p1b0, p1w1, p1b1, ev,
                       stage, sid_arr, cnt_arr, use_stage);
    if (use_stage) {
        hipLaunchKernelGGL(k1_combine, dim3(K1_WAVES / 4), dim3(256), 0, stream,
                           stage, sid_arr, cnt_arr, ev);
    }
    hipLaunchKernelGGL(k2_events, dim3((NE + 63) / 64), dim3(64), 0, stream,
                       ev, r1w0, r1b0, r1w1, r1b1, o1w, o1b,
                       p2w0, p2b0, p2w1, p2b1, s2);
    hipLaunchKernelGGL(k3_final, dim3(1), dim3(64), 0, stream,
                       s2, r2w0, r2b0, r2w1, r2b1, o2w, o2b, (float*)d_out);
}

// Round 10
// 72.681 us; speedup vs baseline: 2.1233x; 1.0044x over previous
//
#include <hip/hip_runtime.h>

#define NT 2000000
#define NE 20000
#define NTILES (NT / 64)      // 31250, exact
#define K1_BLOCKS 1024
#define K1_WAVES (K1_BLOCKS * 4)   // 4096
#define TILES_BASE (NTILES / K1_WAVES)          // 7
#define TILES_REM (NTILES - TILES_BASE * K1_WAVES)  // 2578
#define STAGE_CAP 24          // avg flushes/wave ~7.5; overflow -> atomic
#define ZERO_FLOATS (NE * 64 + 64)              // ev + s2, contiguous
#define ZERO_VEC4 (ZERO_FLOATS / 4)             // 320016, exact

using bf16x8 = __attribute__((ext_vector_type(8))) __bf16;
using half8  = __attribute__((ext_vector_type(8))) _Float16;
using half2v = __attribute__((ext_vector_type(2))) _Float16;
using f32x4  = __attribute__((ext_vector_type(4))) float;
using f32x2  = __attribute__((ext_vector_type(2))) float;
using fvec4  = __attribute__((ext_vector_type(4))) float;

// hi/lo bf16 split of 8 consecutive f32 (k2 precision)
__device__ __forceinline__ void load_bsplit(const float* __restrict__ p,
                                            bf16x8& hi, bf16x8& lo) {
    fvec4 a = *(const fvec4*)p;
    fvec4 b = *(const fvec4*)(p + 4);
#pragma unroll
    for (int e = 0; e < 4; e++) {
        float v  = a[e];
        __bf16 h = (__bf16)v;
        hi[e]    = h;
        lo[e]    = (__bf16)(v - (float)h);
        float v2  = b[e];
        __bf16 h2 = (__bf16)v2;
        hi[e + 4] = h2;
        lo[e + 4] = (__bf16)(v2 - (float)h2);
    }
}

// 8 consecutive f32 -> f16x8
__device__ __forceinline__ half8 load_h8(const float* __restrict__ p) {
    fvec4 a = *(const fvec4*)p;
    fvec4 b = *(const fvec4*)(p + 4);
    half8 r;
#pragma unroll
    for (int e = 0; e < 4; e++) {
        r[e]     = (_Float16)a[e];
        r[e + 4] = (_Float16)b[e];
    }
    return r;
}

// ---------------- K0: fast zero of ev+s2 (rocclr fillBuffer ran at 121 GB/s,
// 40us -- 55% of the whole pipeline at r9; this is ~2-3us) ----------------
__global__ __launch_bounds__(256) void k0_zero(float* __restrict__ p) {
    const int i = blockIdx.x * 256 + threadIdx.x;
    if (i < ZERO_VEC4) {
        fvec4 z = {0.f, 0.f, 0.f, 0.f};
        *(fvec4*)(p + (size_t)i * 4) = z;
    }
}

// ---------------- K1: fused phi1 (2 layers) + jagged segment-sum ----------------
// Carry + contiguous ranges + STAGED flushes (no atomics in the hot loop).
// r9 confirmed: staged flushes removed the atomic drain wall (k1 now ~20us).
// Tripwire: FETCH_SIZE must stay ~8-11MB (spills showed 120-226MB r2/r5).
__global__ __launch_bounds__(256, 4) void k1_phi1(
    const float* __restrict__ values, const int* __restrict__ seg,
    const float* __restrict__ w0, const float* __restrict__ b0,
    const float* __restrict__ w1, const float* __restrict__ b1,
    float* __restrict__ ev,
    float* __restrict__ stage, int* __restrict__ sid_arr,
    int* __restrict__ cnt_arr, int use_stage) {
    const int tid = threadIdx.x;
    const int w   = tid >> 6;
    const int l   = tid & 63;
    const int l15 = l & 15;
    const int l4  = l >> 4;

    // B fragments for W1 (f16): lane holds col j=16jf+l15, k = 32kf+8*l4+e
    half8 Bh[2][4];
#pragma unroll
    for (int kf = 0; kf < 2; kf++)
#pragma unroll
        for (int jf = 0; jf < 4; jf++)
            Bh[kf][jf] = load_h8(w1 + (jf * 16 + l15) * 64 + kf * 32 + l4 * 8);

    // layer-1 weights as f16 pairs -> v_pk_fma_f16 in the A-build
    half2v w0h[2][4], b0h[2][4];
#pragma unroll
    for (int kf = 0; kf < 2; kf++) {
        const int kb = kf * 32 + l4 * 8;
#pragma unroll
        for (int e2 = 0; e2 < 4; e2++) {
            f32x2 wp = *(const f32x2*)(w0 + kb + 2 * e2);
            f32x2 bp = *(const f32x2*)(b0 + kb + 2 * e2);
            w0h[kf][e2] = half2v{(_Float16)wp[0], (_Float16)wp[1]};
            b0h[kf][e2] = half2v{(_Float16)bp[0], (_Float16)bp[1]};
        }
    }
    // bias as ready-made C fragment
    f32x4 biasC[4];
#pragma unroll
    for (int jf = 0; jf < 4; jf++) {
        const float bj = b1[jf * 16 + l15];
#pragma unroll
        for (int r = 0; r < 4; r++) biasC[jf][r] = bj;
    }

    // 2-step butterfly: lane l ends holding full column sum of feature j==l
    const bool bit0 = (l & 16) != 0;
    const bool bit1 = (l & 32) != 0;
    auto reduce4 = [&](const float sj[4]) -> float {
        float send01 = bit0 ? sj[0] : sj[1];
        float keep01 = bit0 ? sj[1] : sj[0];
        float c01 = keep01 + __shfl_xor(send01, 16);
        float send23 = bit0 ? sj[2] : sj[3];
        float keep23 = bit0 ? sj[3] : sj[2];
        float c23 = keep23 + __shfl_xor(send23, 16);
        float send = bit1 ? c01 : c23;
        float keep = bit1 ? c23 : c01;
        return keep + __shfl_xor(send, 32);
    };

    const int wid   = blockIdx.x * 4 + w;
    const int start = wid * TILES_BASE + (wid < TILES_REM ? wid : TILES_REM);
    const int end   = start + TILES_BASE + (wid < TILES_REM ? 1 : 0);

    int nf = 0;
    auto FLUSH = [&](int sid, float* sj) {
        const float v = reduce4(sj);
        if (use_stage && nf < STAGE_CAP) {
            const int slot = wid * STAGE_CAP + nf;
            stage[(size_t)slot * 64 + l] = v;
            if (l == 0) sid_arr[slot] = sid;
            nf++;
        } else {
            atomicAdd(ev + (size_t)sid * 64 + l, v);
        }
    };

    // preload first tile
    int t = start;
    int s_cur = seg[t * 64 + l];
    half2v vph[2];
#pragma unroll
    for (int b = 0; b < 4; b++)
        vph[b >> 1][b & 1] = (_Float16)values[t * 64 + b * 16 + l15];

    int   cur = __builtin_amdgcn_readlane(s_cur, 0);
    float sj[4] = {0.f, 0.f, 0.f, 0.f};

    while (t < end) {
        // ---- prefetch next tile (uniform guard) ----
        const int nt = t + 1;
        int s_nxt = 0;
        half2v vpn[2];
#pragma unroll
        for (int i = 0; i < 2; i++) vpn[i] = half2v{(_Float16)0.f, (_Float16)0.f};
        if (nt < end) {
            s_nxt = seg[nt * 64 + l];
#pragma unroll
            for (int b = 0; b < 4; b++)
                vpn[b >> 1][b & 1] = (_Float16)values[nt * 64 + b * 16 + l15];
        }

        // boundary mask; lane0 compares against carried event id
        const int prev = __shfl_up(s_cur, 1);
        const bool diff = (l == 0) ? (s_cur != cur) : (s_cur != prev);
        const unsigned long long mask = __ballot(diff);

#pragma unroll
        for (int b = 0; b < 4; b++) {          // 16-row block
            const unsigned mask16 = (unsigned)((mask >> (16 * b)) & 0xFFFFull);
            const _Float16 vh = vph[b >> 1][b & 1];
            const half2v vv = {vh, vh};

            // A frags (both kf): h1 = relu(v*w0+b0) in packed f16
            half8 A0, A1;
#pragma unroll
            for (int e2 = 0; e2 < 4; e2++) {
                half2v h0 = vv * w0h[0][e2] + b0h[0][e2];   // v_pk_fma_f16
                half2v h1 = vv * w0h[1][e2] + b0h[1][e2];
                const _Float16 z = (_Float16)0.f;
                A0[2 * e2]     = h0[0] > z ? h0[0] : z;
                A0[2 * e2 + 1] = h0[1] > z ? h0[1] : z;
                A1[2 * e2]     = h1[0] > z ? h1[0] : z;
                A1[2 * e2 + 1] = h1[1] > z ? h1[1] : z;
            }

            // 2-MFMA chain per jf, relu'd into frag (streaming)
            f32x4 frag[4];
#pragma unroll
            for (int jf = 0; jf < 4; jf++) {
                f32x4 tt = __builtin_amdgcn_mfma_f32_16x16x32_f16(
                    A0, Bh[0][jf], biasC[jf], 0, 0, 0);
                tt = __builtin_amdgcn_mfma_f32_16x16x32_f16(
                    A1, Bh[1][jf], tt, 0, 0, 0);
#pragma unroll
                for (int r = 0; r < 4; r++) frag[jf][r] = fmaxf(tt[r], 0.f);
            }

            if (mask16 == 0u) {
#pragma unroll
                for (int jf = 0; jf < 4; jf++)
                    sj[jf] += (frag[jf][0] + frag[jf][1]) +
                              (frag[jf][2] + frag[jf][3]);
            } else {
                unsigned m = mask16;
                int st = 0;
                while (true) {
                    const int e = m ? (int)__builtin_ctz(m) : 16;
#pragma unroll
                    for (int jf = 0; jf < 4; jf++) {
                        float s = 0.f;
#pragma unroll
                        for (int r = 0; r < 4; r++) {
                            const int rel = l4 * 4 + r;
                            s += (rel >= st && rel < e) ? frag[jf][r] : 0.f;
                        }
                        sj[jf] += s;
                    }
                    if (!m) break;
                    FLUSH(cur, sj);
                    sj[0] = sj[1] = sj[2] = sj[3] = 0.f;
                    cur = __builtin_amdgcn_readlane(s_cur, 16 * b + e);
                    st  = e;
                    m &= (m - 1);
                }
            }
        }

        // rotate prefetched state (carry cur/sj across tiles)
        t = nt;
        s_cur = s_nxt;
        vph[0] = vpn[0];
        vph[1] = vpn[1];
    }
    FLUSH(cur, sj);                            // range-end flush
    if (use_stage && l == 0) cnt_arr[wid] = nf;
}

// ---------------- K1b: combine staged partials into ev (dependency-free atomics) --
__global__ __launch_bounds__(256) void k1_combine(
    const float* __restrict__ stage, const int* __restrict__ sid_arr,
    const int* __restrict__ cnt_arr, float* __restrict__ ev) {
    const int w = threadIdx.x >> 6, l = threadIdx.x & 63;
    const int wid = blockIdx.x * 4 + w;
    const int n = cnt_arr[wid];
    for (int c = 0; c < n; ++c) {
        const int slot = wid * STAGE_CAP + c;
        const int sid  = sid_arr[slot];
        atomicAdd(ev + (size_t)sid * 64 + l, stage[(size_t)slot * 64 + l]);
    }
}

// ---------------- K2: rho1 + o1 + phi2 (5 fused 64x64 layers) + event-sum --------
__global__ __launch_bounds__(64) void k2_events(
    const float* __restrict__ ev,
    const float* __restrict__ W0, const float* __restrict__ B0,
    const float* __restrict__ W1, const float* __restrict__ B1,
    const float* __restrict__ W2, const float* __restrict__ B2,
    const float* __restrict__ W3, const float* __restrict__ B3,
    const float* __restrict__ W4, const float* __restrict__ B4,
    float* __restrict__ s2) {
    __shared__ __align__(16) __bf16 xt[64 * 72];   // [e][k], stride 72
    const int l   = threadIdx.x;
    const int l15 = l & 15;
    const int l4  = l >> 4;
    const int ebase = blockIdx.x * 64;

    const float* Ws[5] = {W0, W1, W2, W3, W4};
    const float* Bs[5] = {B0, B1, B2, B3, B4};

    bf16x8 A[4][2];
#pragma unroll
    for (int pf = 0; pf < 4; pf++) {
        const int e = ebase + pf * 16 + l15;
#pragma unroll
        for (int kf = 0; kf < 2; kf++) {
            bf16x8 a;
            if (e < NE) {
                const float* p = ev + (size_t)e * 64 + kf * 32 + l4 * 8;
                fvec4 x = *(const fvec4*)p;
                fvec4 y = *(const fvec4*)(p + 4);
#pragma unroll
                for (int e2 = 0; e2 < 4; e2++) {
                    a[e2]     = (__bf16)x[e2];
                    a[e2 + 4] = (__bf16)y[e2];
                }
            } else {
#pragma unroll
                for (int e2 = 0; e2 < 8; e2++) a[e2] = (__bf16)0.f;
            }
            A[pf][kf] = a;
        }
    }

#pragma unroll
    for (int L = 0; L < 5; L++) {
        bf16x8 Bh[2][4], Bl[2][4];
#pragma unroll
        for (int kf = 0; kf < 2; kf++)
#pragma unroll
            for (int jf = 0; jf < 4; jf++)
                load_bsplit(Ws[L] + (jf * 16 + l15) * 64 + kf * 32 + l4 * 8,
                            Bh[kf][jf], Bl[kf][jf]);

        f32x4 acc[4][4];
#pragma unroll
        for (int jf = 0; jf < 4; jf++) {
            const float bj = Bs[L][jf * 16 + l15];
#pragma unroll
            for (int pf = 0; pf < 4; pf++)
#pragma unroll
                for (int r = 0; r < 4; r++) acc[pf][jf][r] = bj;
        }
#pragma unroll
        for (int kf = 0; kf < 2; kf++)
#pragma unroll
            for (int pf = 0; pf < 4; pf++)
#pragma unroll
                for (int jf = 0; jf < 4; jf++)
                    acc[pf][jf] = __builtin_amdgcn_mfma_f32_16x16x32_bf16(
                        A[pf][kf], Bh[kf][jf], acc[pf][jf], 0, 0, 0);
#pragma unroll
        for (int kf = 0; kf < 2; kf++)
#pragma unroll
            for (int pf = 0; pf < 4; pf++)
#pragma unroll
                for (int jf = 0; jf < 4; jf++)
                    acc[pf][jf] = __builtin_amdgcn_mfma_f32_16x16x32_bf16(
                        A[pf][kf], Bl[kf][jf], acc[pf][jf], 0, 0, 0);

        if (L < 4) {
#pragma unroll
            for (int pf = 0; pf < 4; pf++)
#pragma unroll
                for (int jf = 0; jf < 4; jf++) {
                    const int j = jf * 16 + l15;
#pragma unroll
                    for (int r = 0; r < 4; r++)
                        xt[(pf * 16 + l4 * 4 + r) * 72 + j] =
                            (__bf16)fmaxf(acc[pf][jf][r], 0.f);
                }
#pragma unroll
            for (int pf = 0; pf < 4; pf++)
#pragma unroll
                for (int kf = 0; kf < 2; kf++)
                    A[pf][kf] = *(const bf16x8*)(xt + (pf * 16 + l15) * 72 +
                                                 kf * 32 + l4 * 8);
        } else {
            float sj[4];
#pragma unroll
            for (int jf = 0; jf < 4; jf++) {
                float s = 0.f;
#pragma unroll
                for (int pf = 0; pf < 4; pf++)
#pragma unroll
                    for (int r = 0; r < 4; r++) {
                        const int e = ebase + pf * 16 + l4 * 4 + r;
                        float v = fmaxf(acc[pf][jf][r], 0.f);
                        s += (e < NE) ? v : 0.f;
                    }
                s += __shfl_xor(s, 16);
                s += __shfl_xor(s, 32);
                sj[jf] = s;
            }
            float v = (l4 == 0) ? sj[0] : (l4 == 1) ? sj[1]
                    : (l4 == 2) ? sj[2] : sj[3];
            atomicAdd(s2 + l, v);
        }
    }
}

// ---------------- K3: rho2 + output + log_softmax (tiny) ----------------
__global__ __launch_bounds__(64) void k3_final(
    const float* __restrict__ s2,
    const float* __restrict__ W0, const float* __restrict__ B0,
    const float* __restrict__ W1, const float* __restrict__ B1,
    const float* __restrict__ W2, const float* __restrict__ B2,
    float* __restrict__ out) {
    __shared__ __align__(16) float xb[64];
    __shared__ __align__(16) float yb[64];
    __shared__ float ob[10];
    const int l = threadIdx.x;

    xb[l] = s2[l];
    __syncthreads();

    float a = B0[l];
#pragma unroll
    for (int k = 0; k < 16; k++) {
        fvec4 wv = *(const fvec4*)(W0 + l * 64 + k * 4);
        fvec4 xv = *(const fvec4*)(xb + k * 4);
        a += wv[0] * xv[0] + wv[1] * xv[1] + wv[2] * xv[2] + wv[3] * xv[3];
    }
    yb[l] = fmaxf(a, 0.f);
    __syncthreads();

    float b_ = B1[l];
#pragma unroll
    for (int k = 0; k < 16; k++) {
        fvec4 wv = *(const fvec4*)(W1 + l * 64 + k * 4);
        fvec4 xv = *(const fvec4*)(yb + k * 4);
        b_ += wv[0] * xv[0] + wv[1] * xv[1] + wv[2] * xv[2] + wv[3] * xv[3];
    }
    __syncthreads();
    xb[l] = fmaxf(b_, 0.f);
    __syncthreads();

    if (l < 10) {
        float o = B2[l];
#pragma unroll
        for (int k = 0; k < 16; k++) {
            fvec4 wv = *(const fvec4*)(W2 + l * 64 + k * 4);
            fvec4 xv = *(const fvec4*)(xb + k * 4);
            o += wv[0] * xv[0] + wv[1] * xv[1] + wv[2] * xv[2] + wv[3] * xv[3];
        }
        ob[l] = o;
    }
    __syncthreads();
    if (l == 0) {
        float m = ob[0];
#pragma unroll
        for (int i = 1; i < 10; i++) m = fmaxf(m, ob[i]);
        float sum = 0.f;
#pragma unroll
        for (int i = 0; i < 10; i++) sum = sum + expf(ob[i] - m);
        float ls = logf(sum);
#pragma unroll
        for (int i = 0; i < 10; i++) out[i] = ob[i] - m - ls;
    }
}

extern "C" void kernel_launch(void* const* d_in, const int* in_sizes, int n_in,
                              void* d_out, int out_size, void* d_ws, size_t ws_size,
                              hipStream_t stream) {
    const float* values = (const float*)d_in[0];
    const int*   seg    = (const int*)d_in[1];
    const float* p1w0 = (const float*)d_in[2],  *p1b0 = (const float*)d_in[3];
    const float* p1w1 = (const float*)d_in[4],  *p1b1 = (const float*)d_in[5];
    const float* r1w0 = (const float*)d_in[6],  *r1b0 = (const float*)d_in[7];
    const float* r1w1 = (const float*)d_in[8],  *r1b1 = (const float*)d_in[9];
    const float* o1w  = (const float*)d_in[10], *o1b  = (const float*)d_in[11];
    const float* p2w0 = (const float*)d_in[12], *p2b0 = (const float*)d_in[13];
    const float* p2w1 = (const float*)d_in[14], *p2b1 = (const float*)d_in[15];
    const float* r2w0 = (const float*)d_in[16], *r2b0 = (const float*)d_in[17];
    const float* r2w1 = (const float*)d_in[18], *r2b1 = (const float*)d_in[19];
    const float* o2w  = (const float*)d_in[20], *o2b  = (const float*)d_in[21];

    float* ev = (float*)d_ws;                       // [NE][64] accumulators
    float* s2 = ev + (size_t)NE * 64;               // [64]
    int*   cnt_arr = (int*)(s2 + 64);               // [K1_WAVES]
    int*   sid_arr = cnt_arr + K1_WAVES;            // [K1_WAVES*STAGE_CAP]
    float* stage   = (float*)(sid_arr + (size_t)K1_WAVES * STAGE_CAP);

    const size_t need = ((size_t)NE * 64 + 64) * 4 +
                        (size_t)K1_WAVES * 4 +
                        (size_t)K1_WAVES * STAGE_CAP * 4 +
                        (size_t)K1_WAVES * STAGE_CAP * 64 * 4;   // ~30.7 MB
    const int use_stage = (ws_size >= need) ? 1 : 0;

    hipLaunchKernelGGL(k0_zero, dim3((ZERO_VEC4 + 255) / 256), dim3(256), 0,
                       stream, (float*)d_ws);

    hipLaunchKernelGGL(k1_phi1, dim3(K1_BLOCKS), dim3(256), 0, stream,
                       values, seg, p1w0, p1b0, p1w1, p1b1, ev,
                       stage, sid_arr, cnt_arr, use_stage);
    if (use_stage) {
        hipLaunchKernelGGL(k1_combine, dim3(K1_WAVES / 4), dim3(256), 0, stream,
                           stage, sid_arr, cnt_arr, ev);
    }
    hipLaunchKernelGGL(k2_events, dim3((NE + 63) / 64), dim3(64), 0, stream,
                       ev, r1w0, r1b0, r1w1, r1b1, o1w, o1b,
                       p2w0, p2b0, p2w1, p2b1, s2);
    hipLaunchKernelGGL(k3_final, dim3(1), dim3(64), 0, stream,
                       s2, r2w0, r2b0, r2w1, r2b1, o2w, o2b, (float*)d_out);
}

// Round 11
// 71.873 us; speedup vs baseline: 2.1472x; 1.0112x over previous
//
#include <hip/hip_runtime.h>

#define NT 2000000
#define NE 20000
#define NT4 (NT / 4)          // 500000, exact
#define EPW 5                 // events per wave; 4096 waves x 5 = 20480 >= NE

using bf16x8 = __attribute__((ext_vector_type(8))) __bf16;
using half8  = __attribute__((ext_vector_type(8))) _Float16;
using half2v = __attribute__((ext_vector_type(2))) _Float16;
using f32x4  = __attribute__((ext_vector_type(4))) float;
using f32x2  = __attribute__((ext_vector_type(2))) float;
using fvec4  = __attribute__((ext_vector_type(4))) float;

// hi/lo bf16 split of 8 consecutive f32 (k2 precision)
__device__ __forceinline__ void load_bsplit(const float* __restrict__ p,
                                            bf16x8& hi, bf16x8& lo) {
    fvec4 a = *(const fvec4*)p;
    fvec4 b = *(const fvec4*)(p + 4);
#pragma unroll
    for (int e = 0; e < 4; e++) {
        float v  = a[e];
        __bf16 h = (__bf16)v;
        hi[e]    = h;
        lo[e]    = (__bf16)(v - (float)h);
        float v2  = b[e];
        __bf16 h2 = (__bf16)v2;
        hi[e + 4] = h2;
        lo[e + 4] = (__bf16)(v2 - (float)h2);
    }
}

// 8 consecutive f32 -> f16x8
__device__ __forceinline__ half8 load_h8(const float* __restrict__ p) {
    fvec4 a = *(const fvec4*)p;
    fvec4 b = *(const fvec4*)(p + 4);
    half8 r;
#pragma unroll
    for (int e = 0; e < 4; e++) {
        r[e]     = (_Float16)a[e];
        r[e + 4] = (_Float16)b[e];
    }
    return r;
}

// ---------------- K0: event offsets via boundary scatter + zero s2 ----------------
// off[e] = first particle index i with seg[i] >= e; off[NE] = NT. Handles empty
// events (off[e]==off[e+1]) and head/tail gaps exactly.
__global__ __launch_bounds__(256) void k0_offsets(
    const int* __restrict__ seg, int* __restrict__ off, float* __restrict__ s2) {
    if (blockIdx.x == 0 && threadIdx.x < 64) s2[threadIdx.x] = 0.f;
    const int g = blockIdx.x * 256 + threadIdx.x;
    if (g >= NT4) return;
    const int idx4 = g * 4;
    const int4 s = *(const int4*)(seg + idx4);
    int prev = (g == 0) ? -1 : seg[idx4 - 1];
    int vals[4] = {s.x, s.y, s.z, s.w};
#pragma unroll
    for (int k = 0; k < 4; k++) {
        const int cur = vals[k];
        if (cur != prev) {
            for (int e = prev + 1; e <= cur; ++e) off[e] = idx4 + k;
        }
        prev = cur;
    }
    if (idx4 + 3 == NT - 1) {
        for (int e = prev + 1; e <= NE; ++e) off[e] = NT;
    }
}

// ---------------- K1: fused phi1 (2 layers) + per-event sum, WAVE PER EVENT ------
// seg sorted -> events contiguous (n ~ Poisson(100)). One wave owns one event:
// no ballot/readlane/run-loop/atomics/staging (r7-r10 showed that segmented
// machinery, not FLOPs, dominated: k1 sat ~40-47us vs ~6.5us instr floor).
// Plain coalesced store of the 64-float event vector; ev needs NO zeroing.
__global__ __launch_bounds__(256, 4) void k1_phi1(
    const float* __restrict__ values, const int* __restrict__ off,
    const float* __restrict__ w0, const float* __restrict__ b0,
    const float* __restrict__ w1, const float* __restrict__ b1,
    float* __restrict__ ev) {
    const int tid = threadIdx.x;
    const int w   = tid >> 6;
    const int l   = tid & 63;
    const int l15 = l & 15;
    const int l4  = l >> 4;

    // B fragments for W1 (f16): lane holds col j=16jf+l15, k = 32kf+8*l4+e
    half8 Bh[2][4];
#pragma unroll
    for (int kf = 0; kf < 2; kf++)
#pragma unroll
        for (int jf = 0; jf < 4; jf++)
            Bh[kf][jf] = load_h8(w1 + (jf * 16 + l15) * 64 + kf * 32 + l4 * 8);

    // layer-1 weights as f16 pairs -> v_pk_fma_f16 in the A-build
    half2v w0h[2][4], b0h[2][4];
#pragma unroll
    for (int kf = 0; kf < 2; kf++) {
        const int kb = kf * 32 + l4 * 8;
#pragma unroll
        for (int e2 = 0; e2 < 4; e2++) {
            f32x2 wp = *(const f32x2*)(w0 + kb + 2 * e2);
            f32x2 bp = *(const f32x2*)(b0 + kb + 2 * e2);
            w0h[kf][e2] = half2v{(_Float16)wp[0], (_Float16)wp[1]};
            b0h[kf][e2] = half2v{(_Float16)bp[0], (_Float16)bp[1]};
        }
    }
    // bias as ready-made C fragment
    f32x4 biasC[4];
#pragma unroll
    for (int jf = 0; jf < 4; jf++) {
        const float bj = b1[jf * 16 + l15];
#pragma unroll
        for (int r = 0; r < 4; r++) biasC[jf][r] = bj;
    }

    // 2-step butterfly: lane l ends holding full column sum of feature j==l
    const bool bit0 = (l & 16) != 0;
    const bool bit1 = (l & 32) != 0;
    auto reduce4 = [&](const float sj[4]) -> float {
        float send01 = bit0 ? sj[0] : sj[1];
        float keep01 = bit0 ? sj[1] : sj[0];
        float c01 = keep01 + __shfl_xor(send01, 16);
        float send23 = bit0 ? sj[2] : sj[3];
        float keep23 = bit0 ? sj[3] : sj[2];
        float c23 = keep23 + __shfl_xor(send23, 16);
        float send = bit1 ? c01 : c23;
        float keep = bit1 ? c23 : c01;
        return keep + __shfl_xor(send, 32);
    };

    const int wid = blockIdx.x * 4 + w;          // 4096 waves
    const int e0  = wid * EPW;

    for (int e = e0; e < e0 + EPW && e < NE; ++e) {
        const int s = off[e];
        const int t = off[e + 1];
        const int n = t - s;
        float sj[4] = {0.f, 0.f, 0.f, 0.f};

        if (n > 0) {
            const int nblk = (n + 15) >> 4;
            int idx = s + l15;
            _Float16 vcur = (_Float16)((idx < t) ? values[idx] : 0.f);

            for (int b = 0; b < nblk; ++b) {
                // prefetch next block's value
                const int idxn = s + (b + 1) * 16 + l15;
                const _Float16 vnxt =
                    (_Float16)((b + 1 < nblk && idxn < t) ? values[idxn] : 0.f);

                // A frags (both kf): h1 = relu(v*w0+b0) in packed f16
                const half2v vv = {vcur, vcur};
                half8 A0, A1;
#pragma unroll
                for (int e2 = 0; e2 < 4; e2++) {
                    half2v h0 = vv * w0h[0][e2] + b0h[0][e2];   // v_pk_fma_f16
                    half2v h1 = vv * w0h[1][e2] + b0h[1][e2];
                    const _Float16 z = (_Float16)0.f;
                    A0[2 * e2]     = h0[0] > z ? h0[0] : z;
                    A0[2 * e2 + 1] = h0[1] > z ? h0[1] : z;
                    A1[2 * e2]     = h1[0] > z ? h1[0] : z;
                    A1[2 * e2 + 1] = h1[1] > z ? h1[1] : z;
                }

                // 2-MFMA chain per jf, relu'd into frag (streaming)
                f32x4 frag[4];
#pragma unroll
                for (int jf = 0; jf < 4; jf++) {
                    f32x4 tt = __builtin_amdgcn_mfma_f32_16x16x32_f16(
                        A0, Bh[0][jf], biasC[jf], 0, 0, 0);
                    tt = __builtin_amdgcn_mfma_f32_16x16x32_f16(
                        A1, Bh[1][jf], tt, 0, 0, 0);
#pragma unroll
                    for (int r = 0; r < 4; r++) frag[jf][r] = fmaxf(tt[r], 0.f);
                }

                const int rem = n - b * 16;
                if (rem >= 16) {
#pragma unroll
                    for (int jf = 0; jf < 4; jf++)
                        sj[jf] += (frag[jf][0] + frag[jf][1]) +
                                  (frag[jf][2] + frag[jf][3]);
                } else {
                    // tail: select-mask (NOT multiply -- garbage rows may be inf)
#pragma unroll
                    for (int r = 0; r < 4; r++) {
                        const bool ok = (l4 * 4 + r) < rem;
#pragma unroll
                        for (int jf = 0; jf < 4; jf++)
                            sj[jf] += ok ? frag[jf][r] : 0.f;
                    }
                }
                vcur = vnxt;
            }
        }
        // plain coalesced store; exactly one wave owns event e
        ev[(size_t)e * 64 + l] = reduce4(sj);
    }
}

// ---------------- K2: rho1 + o1 + phi2 (5 fused 64x64 layers) + event-sum --------
__global__ __launch_bounds__(64) void k2_events(
    const float* __restrict__ ev,
    const float* __restrict__ W0, const float* __restrict__ B0,
    const float* __restrict__ W1, const float* __restrict__ B1,
    const float* __restrict__ W2, const float* __restrict__ B2,
    const float* __restrict__ W3, const float* __restrict__ B3,
    const float* __restrict__ W4, const float* __restrict__ B4,
    float* __restrict__ s2) {
    __shared__ __align__(16) __bf16 xt[64 * 72];   // [e][k], stride 72
    const int l   = threadIdx.x;
    const int l15 = l & 15;
    const int l4  = l >> 4;
    const int ebase = blockIdx.x * 64;

    const float* Ws[5] = {W0, W1, W2, W3, W4};
    const float* Bs[5] = {B0, B1, B2, B3, B4};

    bf16x8 A[4][2];
#pragma unroll
    for (int pf = 0; pf < 4; pf++) {
        const int e = ebase + pf * 16 + l15;
#pragma unroll
        for (int kf = 0; kf < 2; kf++) {
            bf16x8 a;
            if (e < NE) {
                const float* p = ev + (size_t)e * 64 + kf * 32 + l4 * 8;
                fvec4 x = *(const fvec4*)p;
                fvec4 y = *(const fvec4*)(p + 4);
#pragma unroll
                for (int e2 = 0; e2 < 4; e2++) {
                    a[e2]     = (__bf16)x[e2];
                    a[e2 + 4] = (__bf16)y[e2];
                }
            } else {
#pragma unroll
                for (int e2 = 0; e2 < 8; e2++) a[e2] = (__bf16)0.f;
            }
            A[pf][kf] = a;
        }
    }

#pragma unroll
    for (int L = 0; L < 5; L++) {
        bf16x8 Bh[2][4], Bl[2][4];
#pragma unroll
        for (int kf = 0; kf < 2; kf++)
#pragma unroll
            for (int jf = 0; jf < 4; jf++)
                load_bsplit(Ws[L] + (jf * 16 + l15) * 64 + kf * 32 + l4 * 8,
                            Bh[kf][jf], Bl[kf][jf]);

        f32x4 acc[4][4];
#pragma unroll
        for (int jf = 0; jf < 4; jf++) {
            const float bj = Bs[L][jf * 16 + l15];
#pragma unroll
            for (int pf = 0; pf < 4; pf++)
#pragma unroll
                for (int r = 0; r < 4; r++) acc[pf][jf][r] = bj;
        }
#pragma unroll
        for (int kf = 0; kf < 2; kf++)
#pragma unroll
            for (int pf = 0; pf < 4; pf++)
#pragma unroll
                for (int jf = 0; jf < 4; jf++)
                    acc[pf][jf] = __builtin_amdgcn_mfma_f32_16x16x32_bf16(
                        A[pf][kf], Bh[kf][jf], acc[pf][jf], 0, 0, 0);
#pragma unroll
        for (int kf = 0; kf < 2; kf++)
#pragma unroll
            for (int pf = 0; pf < 4; pf++)
#pragma unroll
                for (int jf = 0; jf < 4; jf++)
                    acc[pf][jf] = __builtin_amdgcn_mfma_f32_16x16x32_bf16(
                        A[pf][kf], Bl[kf][jf], acc[pf][jf], 0, 0, 0);

        if (L < 4) {
#pragma unroll
            for (int pf = 0; pf < 4; pf++)
#pragma unroll
                for (int jf = 0; jf < 4; jf++) {
                    const int j = jf * 16 + l15;
#pragma unroll
                    for (int r = 0; r < 4; r++)
                        xt[(pf * 16 + l4 * 4 + r) * 72 + j] =
                            (__bf16)fmaxf(acc[pf][jf][r], 0.f);
                }
#pragma unroll
            for (int pf = 0; pf < 4; pf++)
#pragma unroll
                for (int kf = 0; kf < 2; kf++)
                    A[pf][kf] = *(const bf16x8*)(xt + (pf * 16 + l15) * 72 +
                                                 kf * 32 + l4 * 8);
        } else {
            float sj[4];
#pragma unroll
            for (int jf = 0; jf < 4; jf++) {
                float s = 0.f;
#pragma unroll
                for (int pf = 0; pf < 4; pf++)
#pragma unroll
                    for (int r = 0; r < 4; r++) {
                        const int e = ebase + pf * 16 + l4 * 4 + r;
                        float v = fmaxf(acc[pf][jf][r], 0.f);
                        s += (e < NE) ? v : 0.f;
                    }
                s += __shfl_xor(s, 16);
                s += __shfl_xor(s, 32);
                sj[jf] = s;
            }
            float v = (l4 == 0) ? sj[0] : (l4 == 1) ? sj[1]
                    : (l4 == 2) ? sj[2] : sj[3];
            atomicAdd(s2 + l, v);
        }
    }
}

// ---------------- K3: rho2 + output + log_softmax (tiny) ----------------
__global__ __launch_bounds__(64) void k3_final(
    const float* __restrict__ s2,
    const float* __restrict__ W0, const float* __restrict__ B0,
    const float* __restrict__ W1, const float* __restrict__ B1,
    const float* __restrict__ W2, const float* __restrict__ B2,
    float* __restrict__ out) {
    __shared__ __align__(16) float xb[64];
    __shared__ __align__(16) float yb[64];
    __shared__ float ob[10];
    const int l = threadIdx.x;

    xb[l] = s2[l];
    __syncthreads();

    float a = B0[l];
#pragma unroll
    for (int k = 0; k < 16; k++) {
        fvec4 wv = *(const fvec4*)(W0 + l * 64 + k * 4);
        fvec4 xv = *(const fvec4*)(xb + k * 4);
        a += wv[0] * xv[0] + wv[1] * xv[1] + wv[2] * xv[2] + wv[3] * xv[3];
    }
    yb[l] = fmaxf(a, 0.f);
    __syncthreads();

    float b_ = B1[l];
#pragma unroll
    for (int k = 0; k < 16; k++) {
        fvec4 wv = *(const fvec4*)(W1 + l * 64 + k * 4);
        fvec4 xv = *(const fvec4*)(yb + k * 4);
        b_ += wv[0] * xv[0] + wv[1] * xv[1] + wv[2] * xv[2] + wv[3] * xv[3];
    }
    __syncthreads();
    xb[l] = fmaxf(b_, 0.f);
    __syncthreads();

    if (l < 10) {
        float o = B2[l];
#pragma unroll
        for (int k = 0; k < 16; k++) {
            fvec4 wv = *(const fvec4*)(W2 + l * 64 + k * 4);
            fvec4 xv = *(const fvec4*)(xb + k * 4);
            o += wv[0] * xv[0] + wv[1] * xv[1] + wv[2] * xv[2] + wv[3] * xv[3];
        }
        ob[l] = o;
    }
    __syncthreads();
    if (l == 0) {
        float m = ob[0];
#pragma unroll
        for (int i = 1; i < 10; i++) m = fmaxf(m, ob[i]);
        float sum = 0.f;
#pragma unroll
        for (int i = 0; i < 10; i++) sum = sum + expf(ob[i] - m);
        float ls = logf(sum);
#pragma unroll
        for (int i = 0; i < 10; i++) out[i] = ob[i] - m - ls;
    }
}

extern "C" void kernel_launch(void* const* d_in, const int* in_sizes, int n_in,
                              void* d_out, int out_size, void* d_ws, size_t ws_size,
                              hipStream_t stream) {
    const float* values = (const float*)d_in[0];
    const int*   seg    = (const int*)d_in[1];
    const float* p1w0 = (const float*)d_in[2],  *p1b0 = (const float*)d_in[3];
    const float* p1w1 = (const float*)d_in[4],  *p1b1 = (const float*)d_in[5];
    const float* r1w0 = (const float*)d_in[6],  *r1b0 = (const float*)d_in[7];
    const float* r1w1 = (const float*)d_in[8],  *r1b1 = (const float*)d_in[9];
    const float* o1w  = (const float*)d_in[10], *o1b  = (const float*)d_in[11];
    const float* p2w0 = (const float*)d_in[12], *p2b0 = (const float*)d_in[13];
    const float* p2w1 = (const float*)d_in[14], *p2b1 = (const float*)d_in[15];
    const float* r2w0 = (const float*)d_in[16], *r2b0 = (const float*)d_in[17];
    const float* r2w1 = (const float*)d_in[18], *r2b1 = (const float*)d_in[19];
    const float* o2w  = (const float*)d_in[20], *o2b  = (const float*)d_in[21];

    float* ev  = (float*)d_ws;                      // [NE][64]
    float* s2  = ev + (size_t)NE * 64;              // [64]
    int*   off = (int*)(s2 + 64);                   // [NE+1]

    hipLaunchKernelGGL(k0_offsets, dim3((NT4 + 255) / 256), dim3(256), 0, stream,
                       seg, off, s2);
    hipLaunchKernelGGL(k1_phi1, dim3(1024), dim3(256), 0, stream,
                       values, off, p1w0, p1b0, p1w1, p1b1, ev);
    hipLaunchKernelGGL(k2_events, dim3((NE + 63) / 64), dim3(64), 0, stream,
                       ev, r1w0, r1b0, r1w1, r1b1, o1w, o1b,
                       p2w0, p2b0, p2w1, p2b1, s2);
    hipLaunchKernelGGL(k3_final, dim3(1), dim3(64), 0, stream,
                       s2, r2w0, r2b0, r2w1, r2b1, o2w, o2b, (float*)d_out);
}